// Round 2
// baseline (432.107 us; speedup 1.0000x reference)
//
#include <hip/hip_runtime.h>
#include <hip/hip_bf16.h>

// Problem constants
#define NB 16384      // batch rows
#define DD 512        // IN+OUT
#define NCOLS 4096    // 4*OUT*NCELL

typedef __attribute__((ext_vector_type(8))) short short8;
typedef __attribute__((ext_vector_type(4))) float f32x4;

__device__ __forceinline__ float sigmoidf_(float x) {
    return 1.f / (1.f + __expf(-x));
}
__device__ __forceinline__ float tanhf_(float x) {
    float e = __expf(-2.f * fabsf(x));      // in (0,1], no overflow
    float t = (1.f - e) / (1.f + e);
    return copysignf(t, x);
}

#define GLOAD_LDS16(g, l) __builtin_amdgcn_global_load_lds( \
    (__attribute__((address_space(1))) void*)(g), \
    (__attribute__((address_space(3))) void*)(l), 16, 0, 0)

// ---------------- P1: feats (concat x,h) -> bf16  +  ctrl logits -> top2 gates ----
// One wave per row (4 waves/block). Reuses the loaded f32 row for the ctrl dot.
__global__ void k_prep(const float* __restrict__ x, const float* __restrict__ h,
                       const float* __restrict__ Wc, const float* __restrict__ bc,
                       __hip_bfloat16* __restrict__ featsB, float* __restrict__ gates) {
    int wave = (blockIdx.x * blockDim.x + threadIdx.x) >> 6;  // == row
    int lane = threadIdx.x & 63;
    int row = wave;
    int k0 = lane * 8;
    const float* src = (k0 < 256) ? (x + (size_t)row * 256 + k0)
                                  : (h + (size_t)row * 256 + k0 - 256);
    float4 f0 = ((const float4*)src)[0];
    float4 f1 = ((const float4*)src)[1];
    float fv[8] = {f0.x, f0.y, f0.z, f0.w, f1.x, f1.y, f1.z, f1.w};
    // bf16 store
    __hip_bfloat16 tmp[8];
#pragma unroll
    for (int j = 0; j < 8; ++j) tmp[j] = __float2bfloat16(fv[j]);
    *reinterpret_cast<short8*>(featsB + (size_t)row * 512 + k0) =
        *reinterpret_cast<short8*>(tmp);
    // ctrl partial dot (f32 — selection must match numpy)
    float acc[4] = {0.f, 0.f, 0.f, 0.f};
#pragma unroll
    for (int j = 0; j < 8; ++j) {
        float4 w = ((const float4*)Wc)[k0 + j];
        acc[0] += fv[j] * w.x; acc[1] += fv[j] * w.y;
        acc[2] += fv[j] * w.z; acc[3] += fv[j] * w.w;
    }
#pragma unroll
    for (int off = 32; off; off >>= 1) {
#pragma unroll
        for (int c = 0; c < 4; ++c) acc[c] += __shfl_xor(acc[c], off);
    }
    if (lane == 0) {
        float l[4];
#pragma unroll
        for (int c = 0; c < 4; ++c) l[c] = acc[c] + bc[c];
        int i1 = 0;
#pragma unroll
        for (int c = 1; c < 4; ++c) if (l[c] > l[i1]) i1 = c;   // ties -> lowest idx
        int i2 = -1;
#pragma unroll
        for (int c = 0; c < 4; ++c)
            if (c != i1 && (i2 < 0 || l[c] > l[i2])) i2 = c;
        float e = __expf(l[i2] - l[i1]);   // <= 1
        float p1 = 1.f / (1.f + e);
        float p2 = e / (1.f + e);
        float g[4] = {0.f, 0.f, 0.f, 0.f};
        g[i1] = p1; g[i2] = p2;
        float4 gv; gv.x = g[0]; gv.y = g[1]; gv.z = g[2]; gv.w = g[3];
        *(float4*)(gates + (size_t)row * 4) = gv;
    }
}

// ---------------- P2: W_gates -> bf16, permuted + transposed ----------------
// W2 layout: [c2g][k], c2g = o_blk*256 + (cell*4+gate)*16 + oi   (4096 x 512 bf16)
// Coalesced READS (consecutive threads -> consecutive cols), 16-B scattered writes.
__global__ void k_repack_w(const float* __restrict__ Wg, __hip_bfloat16* __restrict__ W2) {
    int t = blockIdx.x * blockDim.x + threadIdx.x;   // 262,144 threads
    int k0 = (t >> 12) * 8;
    int col = t & 4095;
    int cell = col >> 10, gate = (col >> 8) & 3, o_blk = (col >> 4) & 15, oi = col & 15;
    int c2g = o_blk * 256 + (cell * 4 + gate) * 16 + oi;
    __hip_bfloat16 tmp[8];
#pragma unroll
    for (int j = 0; j < 8; ++j)
        tmp[j] = __float2bfloat16(Wg[(size_t)(k0 + j) * 4096 + col]);
    *reinterpret_cast<short8*>(W2 + (size_t)c2g * 512 + k0) = *reinterpret_cast<short8*>(tmp);
}

// ---------------- Main fused GEMM + LSTM epilogue ----------------
#define BM 128
#define BN 256
#define BK 64

__launch_bounds__(512, 6)
__global__ void k_main(const __hip_bfloat16* __restrict__ featsB,
                       const __hip_bfloat16* __restrict__ W2,
                       const float* __restrict__ cin,
                       const float* __restrict__ gates,
                       const float* __restrict__ bg,
                       float* __restrict__ out) {
    // 48 KB total: As 16 KB | Bs 32 KB. oAcc (16 KB) aliases As after the K-loop.
    __shared__ char smem[(BM + BN) * BK * 2];
    char* As = smem;                      // [128 rows][64 k] bf16, XOR-swizzled
    char* Bs = smem + BM * BK * 2;        // [256 c2 ][64 k] bf16, XOR-swizzled
    float* oAcc = (float*)smem;           // [2][128][16] f32 (epilogue only)

    int tid = threadIdx.x;
    int wave = tid >> 6, lane = tid & 63;
    int wr = wave >> 2, wc = wave & 3;    // wc == cell index
    int r0 = blockIdx.x * BM;
    int o_blk = blockIdx.y;

    f32x4 acc[4][4];
#pragma unroll
    for (int m = 0; m < 4; ++m)
#pragma unroll
        for (int n = 0; n < 4; ++n)
            acc[m][n] = (f32x4){0.f, 0.f, 0.f, 0.f};

    int hi = lane >> 4;                   // 0..3
    int lsw = lane & 7;                   // read-side XOR key (row&7 == lane&7)

    for (int ks = 0; ks < 8; ++ks) {
        int k0 = ks * BK;
        // stage A: 128x64 bf16 = 1024 16-B chunks; linear LDS dest, swizzled SOURCE
#pragma unroll
        for (int q = 0; q < 2; ++q) {
            int e = q * 512 + tid;
            int row = e >> 3;                         // 8 chunks per 128-B row
            int csw = (e & 7) ^ (row & 7);            // inverse swizzle on source
            GLOAD_LDS16(featsB + (size_t)(r0 + row) * 512 + k0 + csw * 8, As + e * 16);
        }
        // stage B: 256x64 bf16 = 2048 chunks
#pragma unroll
        for (int q = 0; q < 4; ++q) {
            int e = q * 512 + tid;
            int row = e >> 3;
            int csw = (e & 7) ^ (row & 7);
            GLOAD_LDS16(W2 + (size_t)(o_blk * 256 + row) * 512 + k0 + csw * 8, Bs + e * 16);
        }
        __syncthreads();   // drains vmcnt + barrier
#pragma unroll
        for (int kk = 0; kk < 2; ++kk) {
            short8 fa[4], fb[4];
#pragma unroll
            for (int m = 0; m < 4; ++m) {
                int row = wr * 64 + m * 16 + (lane & 15);
                int chunk = (kk * 4 + hi) ^ lsw;      // swizzled read
                fa[m] = *reinterpret_cast<const short8*>(As + row * 128 + chunk * 16);
            }
#pragma unroll
            for (int n = 0; n < 4; ++n) {
                int c2 = wc * 64 + n * 16 + (lane & 15);
                int chunk = (kk * 4 + hi) ^ lsw;
                fb[n] = *reinterpret_cast<const short8*>(Bs + c2 * 128 + chunk * 16);
            }
#pragma unroll
            for (int m = 0; m < 4; ++m)
#pragma unroll
                for (int n = 0; n < 4; ++n)
                    acc[m][n] = __builtin_amdgcn_mfma_f32_16x16x32_bf16(
                        fa[m], fb[n], acc[m][n], 0, 0, 0);
        }
        __syncthreads();
    }

    // Epilogue: wave wc handles cell wc; acc[m][g][reg] = combined(row, gate g)
    // oAcc aliases As — safe: final K-loop __syncthreads fenced all LDS reads.
    for (int i = tid; i < 2 * BM * 16; i += 512) oAcc[i] = 0.f;
    __syncthreads();

    int oi = lane & 15;
    float bb0 = bg[wc * 1024 + 0 * 256 + o_blk * 16 + oi];
    float bb1 = bg[wc * 1024 + 1 * 256 + o_blk * 16 + oi];
    float bb2 = bg[wc * 1024 + 2 * 256 + o_blk * 16 + oi];
    float bb3 = bg[wc * 1024 + 3 * 256 + o_blk * 16 + oi];

#pragma unroll
    for (int m = 0; m < 4; ++m) {
#pragma unroll
        for (int reg = 0; reg < 4; ++reg) {
            int r = wr * 64 + m * 16 + ((lane >> 4) << 2) + reg;
            float gw = gates[(size_t)(r0 + r) * 4 + wc];
            if (gw != 0.f) {
                float iv = sigmoidf_(acc[m][0][reg] + bb0);
                float jv = acc[m][1][reg] + bb1;
                float fv = sigmoidf_(acc[m][2][reg] + bb2);
                float ov = sigmoidf_(acc[m][3][reg] + bb3);
                float cv = cin[(size_t)(r0 + r) * 256 + o_blk * 16 + oi];
                float ncl = fv * cv + iv * tanhf_(jv);
                float nhl = ov * tanhf_(ncl);
                atomicAdd(&oAcc[r * 16 + oi], gw * nhl);
                atomicAdd(&oAcc[BM * 16 + r * 16 + oi], gw * ncl);
            }
        }
    }
    __syncthreads();
    {
        int r = tid >> 2, q = tid & 3;
        size_t ob = (size_t)(r0 + r) * 256 + o_blk * 16 + q * 4;
        *(float4*)&out[ob] = *(float4*)&oAcc[r * 16 + q * 4];
        *(float4*)&out[(size_t)NB * 256 + ob] = *(float4*)&oAcc[BM * 16 + r * 16 + q * 4];
    }
}

extern "C" void kernel_launch(void* const* d_in, const int* in_sizes, int n_in,
                              void* d_out, int out_size, void* d_ws, size_t ws_size,
                              hipStream_t stream) {
    const float* x  = (const float*)d_in[0];
    const float* c  = (const float*)d_in[1];
    const float* h  = (const float*)d_in[2];
    const float* Wg = (const float*)d_in[3];
    const float* bg = (const float*)d_in[4];
    const float* Wc = (const float*)d_in[5];
    const float* bc = (const float*)d_in[6];
    float* out = (float*)d_out;

    const size_t featsB_bytes = (size_t)NB * DD * 2;        // 16.78 MB
    const size_t w2_bytes     = (size_t)NCOLS * DD * 2;     // 4.19 MB
    const size_t gates_bytes  = (size_t)NB * 4 * 4;         // 0.26 MB
    if (ws_size < featsB_bytes + w2_bytes + gates_bytes) return;

    char* ws = (char*)d_ws;
    __hip_bfloat16* featsB = (__hip_bfloat16*)ws;
    __hip_bfloat16* W2     = (__hip_bfloat16*)(ws + featsB_bytes);
    float*          gatesW = (float*)(ws + featsB_bytes + w2_bytes);

    k_prep<<<dim3(4096), dim3(256), 0, stream>>>(x, h, Wc, bc, featsB, gatesW);
    k_repack_w<<<dim3(1024), dim3(256), 0, stream>>>(Wg, W2);
    k_main<<<dim3(NB / BM, 16), dim3(512), 0, stream>>>(featsB, W2, c, gatesW, bg, out);
}

// Round 3
// 170.702 us; speedup vs baseline: 2.5314x; 2.5314x over previous
//
#include <hip/hip_runtime.h>
#include <hip/hip_bf16.h>

// Problem constants
#define NB 16384      // batch rows
#define DD 512        // IN+OUT
#define NCOLS 4096    // 4*OUT*NCELL

typedef __attribute__((ext_vector_type(8))) short short8;
typedef __attribute__((ext_vector_type(4))) float f32x4;

__device__ __forceinline__ float sigmoidf_(float x) {
    return 1.f / (1.f + __expf(-x));
}
__device__ __forceinline__ float tanhf_(float x) {
    float e = __expf(-2.f * fabsf(x));      // in (0,1], no overflow
    float t = (1.f - e) / (1.f + e);
    return copysignf(t, x);
}

#define GLOAD_LDS16(g, l) __builtin_amdgcn_global_load_lds( \
    (__attribute__((address_space(1))) void*)(g), \
    (__attribute__((address_space(3))) void*)(l), 16, 0, 0)

// ---------------- P1: feats (concat x,h) -> bf16  +  ctrl logits -> top2 gates ----
// One wave per row (4 waves/block). Reuses the loaded f32 row for the ctrl dot.
__global__ void k_prep(const float* __restrict__ x, const float* __restrict__ h,
                       const float* __restrict__ Wc, const float* __restrict__ bc,
                       __hip_bfloat16* __restrict__ featsB, float* __restrict__ gates) {
    int wave = (blockIdx.x * blockDim.x + threadIdx.x) >> 6;  // == row
    int lane = threadIdx.x & 63;
    int row = wave;
    int k0 = lane * 8;
    const float* src = (k0 < 256) ? (x + (size_t)row * 256 + k0)
                                  : (h + (size_t)row * 256 + k0 - 256);
    float4 f0 = ((const float4*)src)[0];
    float4 f1 = ((const float4*)src)[1];
    float fv[8] = {f0.x, f0.y, f0.z, f0.w, f1.x, f1.y, f1.z, f1.w};
    // bf16 store
    __hip_bfloat16 tmp[8];
#pragma unroll
    for (int j = 0; j < 8; ++j) tmp[j] = __float2bfloat16(fv[j]);
    *reinterpret_cast<short8*>(featsB + (size_t)row * 512 + k0) =
        *reinterpret_cast<short8*>(tmp);
    // ctrl partial dot (f32 — selection must match numpy)
    float acc[4] = {0.f, 0.f, 0.f, 0.f};
#pragma unroll
    for (int j = 0; j < 8; ++j) {
        float4 w = ((const float4*)Wc)[k0 + j];
        acc[0] += fv[j] * w.x; acc[1] += fv[j] * w.y;
        acc[2] += fv[j] * w.z; acc[3] += fv[j] * w.w;
    }
#pragma unroll
    for (int off = 32; off; off >>= 1) {
#pragma unroll
        for (int c = 0; c < 4; ++c) acc[c] += __shfl_xor(acc[c], off);
    }
    if (lane == 0) {
        float l[4];
#pragma unroll
        for (int c = 0; c < 4; ++c) l[c] = acc[c] + bc[c];
        int i1 = 0;
#pragma unroll
        for (int c = 1; c < 4; ++c) if (l[c] > l[i1]) i1 = c;   // ties -> lowest idx
        int i2 = -1;
#pragma unroll
        for (int c = 0; c < 4; ++c)
            if (c != i1 && (i2 < 0 || l[c] > l[i2])) i2 = c;
        float e = __expf(l[i2] - l[i1]);   // <= 1
        float p1 = 1.f / (1.f + e);
        float p2 = e / (1.f + e);
        float g[4] = {0.f, 0.f, 0.f, 0.f};
        g[i1] = p1; g[i2] = p2;
        float4 gv; gv.x = g[0]; gv.y = g[1]; gv.z = g[2]; gv.w = g[3];
        *(float4*)(gates + (size_t)row * 4) = gv;
    }
}

// ---------------- P2: W_gates -> bf16, permuted + transposed ----------------
// W2 layout: [c2g][k], c2g = o_blk*256 + (cell*4+gate)*16 + oi   (4096 x 512 bf16)
// Coalesced READS (consecutive threads -> consecutive cols), 16-B scattered writes.
__global__ void k_repack_w(const float* __restrict__ Wg, __hip_bfloat16* __restrict__ W2) {
    int t = blockIdx.x * blockDim.x + threadIdx.x;   // 262,144 threads
    int k0 = (t >> 12) * 8;
    int col = t & 4095;
    int cell = col >> 10, gate = (col >> 8) & 3, o_blk = (col >> 4) & 15, oi = col & 15;
    int c2g = o_blk * 256 + (cell * 4 + gate) * 16 + oi;
    __hip_bfloat16 tmp[8];
#pragma unroll
    for (int j = 0; j < 8; ++j)
        tmp[j] = __float2bfloat16(Wg[(size_t)(k0 + j) * 4096 + col]);
    *reinterpret_cast<short8*>(W2 + (size_t)c2g * 512 + k0) = *reinterpret_cast<short8*>(tmp);
}

// ---------------- Main fused GEMM + LSTM epilogue ----------------
#define BM 128
#define BN 256
#define BK 64

// (512, 4): VGPR cap 128 — kernel needs ~80, no spill (R1's (512,6) capped at
// ~85 and spilled the 64-VGPR accumulator -> 1.6 GB scratch traffic).
// Occupancy is LDS-limited anyway: 48 KB -> 3 blocks/CU = 24 waves/CU.
__launch_bounds__(512, 4)
__global__ void k_main(const __hip_bfloat16* __restrict__ featsB,
                       const __hip_bfloat16* __restrict__ W2,
                       const float* __restrict__ cin,
                       const float* __restrict__ gates,
                       const float* __restrict__ bg,
                       float* __restrict__ out) {
    // 48 KB total: As 16 KB | Bs 32 KB. oAcc (16 KB) aliases As after the K-loop.
    __shared__ char smem[(BM + BN) * BK * 2];
    char* As = smem;                      // [128 rows][64 k] bf16, XOR-swizzled
    char* Bs = smem + BM * BK * 2;        // [256 c2 ][64 k] bf16, XOR-swizzled
    float* oAcc = (float*)smem;           // [2][128][16] f32 (epilogue only)

    int tid = threadIdx.x;
    int wave = tid >> 6, lane = tid & 63;
    int wr = wave >> 2, wc = wave & 3;    // wc == cell index
    int r0 = blockIdx.x * BM;
    int o_blk = blockIdx.y;

    f32x4 acc[4][4];
#pragma unroll
    for (int m = 0; m < 4; ++m)
#pragma unroll
        for (int n = 0; n < 4; ++n)
            acc[m][n] = (f32x4){0.f, 0.f, 0.f, 0.f};

    int hi = lane >> 4;                   // 0..3
    int lsw = lane & 7;                   // read-side XOR key (row&7 == lane&7)

    for (int ks = 0; ks < 8; ++ks) {
        int k0 = ks * BK;
        // stage A: 128x64 bf16 = 1024 16-B chunks; linear LDS dest, swizzled SOURCE
#pragma unroll
        for (int q = 0; q < 2; ++q) {
            int e = q * 512 + tid;
            int row = e >> 3;                         // 8 chunks per 128-B row
            int csw = (e & 7) ^ (row & 7);            // inverse swizzle on source
            GLOAD_LDS16(featsB + (size_t)(r0 + row) * 512 + k0 + csw * 8, As + e * 16);
        }
        // stage B: 256x64 bf16 = 2048 chunks
#pragma unroll
        for (int q = 0; q < 4; ++q) {
            int e = q * 512 + tid;
            int row = e >> 3;
            int csw = (e & 7) ^ (row & 7);
            GLOAD_LDS16(W2 + (size_t)(o_blk * 256 + row) * 512 + k0 + csw * 8, Bs + e * 16);
        }
        __syncthreads();   // drains vmcnt + barrier
#pragma unroll
        for (int kk = 0; kk < 2; ++kk) {
            short8 fa[4], fb[4];
#pragma unroll
            for (int m = 0; m < 4; ++m) {
                int row = wr * 64 + m * 16 + (lane & 15);
                int chunk = (kk * 4 + hi) ^ lsw;      // swizzled read
                fa[m] = *reinterpret_cast<const short8*>(As + row * 128 + chunk * 16);
            }
#pragma unroll
            for (int n = 0; n < 4; ++n) {
                int c2 = wc * 64 + n * 16 + (lane & 15);
                int chunk = (kk * 4 + hi) ^ lsw;
                fb[n] = *reinterpret_cast<const short8*>(Bs + c2 * 128 + chunk * 16);
            }
#pragma unroll
            for (int m = 0; m < 4; ++m)
#pragma unroll
                for (int n = 0; n < 4; ++n)
                    acc[m][n] = __builtin_amdgcn_mfma_f32_16x16x32_bf16(
                        fa[m], fb[n], acc[m][n], 0, 0, 0);
        }
        __syncthreads();
    }

    // Epilogue: wave wc handles cell wc; acc[m][g][reg] = combined(row, gate g)
    // oAcc aliases As — safe: final K-loop __syncthreads fenced all LDS reads.
    for (int i = tid; i < 2 * BM * 16; i += 512) oAcc[i] = 0.f;
    __syncthreads();

    int oi = lane & 15;
    float bb0 = bg[wc * 1024 + 0 * 256 + o_blk * 16 + oi];
    float bb1 = bg[wc * 1024 + 1 * 256 + o_blk * 16 + oi];
    float bb2 = bg[wc * 1024 + 2 * 256 + o_blk * 16 + oi];
    float bb3 = bg[wc * 1024 + 3 * 256 + o_blk * 16 + oi];

#pragma unroll
    for (int m = 0; m < 4; ++m) {
#pragma unroll
        for (int reg = 0; reg < 4; ++reg) {
            int r = wr * 64 + m * 16 + ((lane >> 4) << 2) + reg;
            float gw = gates[(size_t)(r0 + r) * 4 + wc];
            if (gw != 0.f) {
                float iv = sigmoidf_(acc[m][0][reg] + bb0);
                float jv = acc[m][1][reg] + bb1;
                float fv = sigmoidf_(acc[m][2][reg] + bb2);
                float ov = sigmoidf_(acc[m][3][reg] + bb3);
                float cv = cin[(size_t)(r0 + r) * 256 + o_blk * 16 + oi];
                float ncl = fv * cv + iv * tanhf_(jv);
                float nhl = ov * tanhf_(ncl);
                atomicAdd(&oAcc[r * 16 + oi], gw * nhl);
                atomicAdd(&oAcc[BM * 16 + r * 16 + oi], gw * ncl);
            }
        }
    }
    __syncthreads();
    {
        int r = tid >> 2, q = tid & 3;
        size_t ob = (size_t)(r0 + r) * 256 + o_blk * 16 + q * 4;
        *(float4*)&out[ob] = *(float4*)&oAcc[r * 16 + q * 4];
        *(float4*)&out[(size_t)NB * 256 + ob] = *(float4*)&oAcc[BM * 16 + r * 16 + q * 4];
    }
}

extern "C" void kernel_launch(void* const* d_in, const int* in_sizes, int n_in,
                              void* d_out, int out_size, void* d_ws, size_t ws_size,
                              hipStream_t stream) {
    const float* x  = (const float*)d_in[0];
    const float* c  = (const float*)d_in[1];
    const float* h  = (const float*)d_in[2];
    const float* Wg = (const float*)d_in[3];
    const float* bg = (const float*)d_in[4];
    const float* Wc = (const float*)d_in[5];
    const float* bc = (const float*)d_in[6];
    float* out = (float*)d_out;

    const size_t featsB_bytes = (size_t)NB * DD * 2;        // 16.78 MB
    const size_t w2_bytes     = (size_t)NCOLS * DD * 2;     // 4.19 MB
    const size_t gates_bytes  = (size_t)NB * 4 * 4;         // 0.26 MB
    if (ws_size < featsB_bytes + w2_bytes + gates_bytes) return;

    char* ws = (char*)d_ws;
    __hip_bfloat16* featsB = (__hip_bfloat16*)ws;
    __hip_bfloat16* W2     = (__hip_bfloat16*)(ws + featsB_bytes);
    float*          gatesW = (float*)(ws + featsB_bytes + w2_bytes);

    k_prep<<<dim3(4096), dim3(256), 0, stream>>>(x, h, Wc, bc, featsB, gatesW);
    k_repack_w<<<dim3(1024), dim3(256), 0, stream>>>(Wg, W2);
    k_main<<<dim3(NB / BM, 16), dim3(512), 0, stream>>>(featsB, W2, c, gatesW, bg, out);
}